// Round 13
// baseline (115.168 us; speedup 1.0000x reference)
//
#include <hip/hip_runtime.h>

// RPN anchor-target assignment. B=8, A=184320, G=64.
// Outputs (flat float32, concatenated): labels[B*A], matched[B*A*4], max_iou[B*A].
// Requires A % 768 == 0 (184320 = 240*768).
//
// Sparse-mask strategy, 3 kernels. Per batch, 4 quantized interval tables
// (u64[128], 5px strips) over the 64 gts; each anchor gets a conservative
// superset mask of possibly-overlapping gts, then exact IEEE IoU only over
// mask bits (~10 avg). Column argmax via LDS u64 atomicMax (order-free exact
// key); block->global device atomicMax.
//
// History: R10 bpermute -> REVERTED. R12 per-pair queue -> REVERTED. R13
// b64+dummies -> REVERTED. R14 counting-sort balancing -> WIN (~40us).
// R15 8 blocks/CU -> win (~38us). R16 gt AoS b128 -> win (~36.5us).
// R17 same-iteration guard reads -> REGRESSION (50us): guard read ~60cy
// before use queued behind hot-column RMW backlogs -> lgkmcnt stalls
// (VALUBusy 37%). R18 coalesced stores via LDS stash -> ~flat (112.9).
//
// R19 (this round): SOFTWARE-PIPELINED monotone guard on column atomics.
//  Diagnosis: the unaccounted ~13us in the cycle model is the u64 LDS
//  atomicMax traffic (15.4M device-wide, 64-scattered-address RMW per
//  instruction). R17 proved naive guards toxic but not guards per se.
//  Fix: extract the NEXT pair's bits at loop top; issue their sgt4 gathers
//  AND skey guard reads there. The guard compare consumes a value loaded a
//  full iteration (~150cy) earlier -> no blocking lgkmcnt. Exactness:
//  skey is monotone (only atomicMax writes); a stale read only under-reads,
//  so skipping when key <= cur is provably a no-op atomic; key > cur always
//  executes. ~95% of atomics (block-local convergence: ~120 updates/column,
//  ~5 actual improvements) collapse to register compares. Dummy prefetch
//  slots (g=63) are READS only — no dummy atomics (R10 lesson).
//  Everything else byte-identical to R18.

constexpr int B = 8;
constexpr int G = 64;
constexpr int BLOCK = 256;
constexpr int APT = 3;                 // anchors per thread
constexpr int ABLK = BLOCK * APT;      // anchors per block = 768
constexpr int NSTRIP = 128;            // 5px strips
constexpr float STRIP_SCALE = 0.2f;
constexpr float STRIP_W = 5.0f;
constexpr float IMG = 640.0f;
constexpr float FG_IOU = 0.7f;
constexpr float BG_IOU = 0.3f;
constexpr float SLACK = 1.0f;
// key(iou=0, anchor=0): correct for an all-zero column (numpy argmax = 0).
constexpr unsigned long long KEY_INIT = 0xFFFFFFFFull;
constexpr unsigned long long TOPBIT = 0x8000000000000000ull;

// ws layout: [256]   u64 gkeys[B*G]      (0xAA poison < 0 as i64 == -inf)
//            [8192]  u64 tabs[B][4][128] (built by build_tables each launch)

// tab0 (xlo): gt.x0 < (s+1)*5 + SLACK   used at s=strip(ax1)  ⊇ gt.x0 < ax1
// tab1 (xhi): gt.x1 > s*5 - SLACK       used at s=strip(ax0)  ⊇ gt.x1 > ax0
// tab2 (ylo): gt.y0 < (s+1)*5 + SLACK   used at s=strip(ay1)  ⊇ gt.y0 < ay1
// tab3 (yhi): gt.y1 > s*5 - SLACK       used at s=strip(ay0)  ⊇ gt.y1 > ay0
__global__ __launch_bounds__(512) void build_tables(
    const float4* __restrict__ gt, unsigned long long* __restrict__ tabs) {
    __shared__ float4 sgt[G];
    const int b = blockIdx.x;
    const int t = threadIdx.x;          // 0..511 = tabIdx*128 + strip
    if (t < G) sgt[t] = gt[b * G + t];
    __syncthreads();
    const int tabIdx = t >> 7;
    const int strip = t & 127;
    const int comp = (tabIdx == 0) ? 0 : (tabIdx == 1) ? 2 : (tabIdx == 2) ? 1 : 3;
    const bool hi = (tabIdx & 1) != 0;
    const float thr = hi ? (strip * STRIP_W - SLACK)
                         : ((strip + 1) * STRIP_W + SLACK);
    unsigned long long m = 0ull;
    for (int g = 0; g < G; ++g) {
        float c = ((const float*)&sgt[g])[comp];
        bool in = hi ? (c > thr) : (c < thr);
        if (in) m |= (1ull << g);
    }
    tabs[(size_t)b * 512 + t] = m;
}

__device__ __forceinline__ int stripclamp(float v) {
    int s = (int)(v * STRIP_SCALE);
    return s < 0 ? 0 : (s > 127 ? 127 : s);
}

__global__ __launch_bounds__(BLOCK, 8) void assign_main(
    const float4* __restrict__ anchors,   // [B*A] cxcywh
    const float4* __restrict__ gt,        // [B*G] xyxy
    float* __restrict__ L,                // labels out [B*A]
    float4* __restrict__ M,               // matched out [B*A]
    float* __restrict__ V,                // max_iou out [B*A]
    long long* __restrict__ gkeys,        // [B*G] global argmax keys (signed max)
    const unsigned long long* __restrict__ tabs,
    int A, int bpb) {
#pragma clang fp contract(off)
    __shared__ float4 sgt4[G];            // gt AoS: ONE b128 read per pair
    __shared__ unsigned long long tab[4][NSTRIP];                 // 4 KB
    __shared__ unsigned long long skey[G];                        // col keys
    __shared__ float sax0[ABLK], say0[ABLK], sax1[ABLK], say1[ABLK]; // 12 KB
    __shared__ unsigned short sidx[ABLK];                         // 1.5 KB
    __shared__ int hist[G];                                       // counts
    __shared__ int pfx[G];                                        // prefix/alloc

    const int b = blockIdx.x / bpb;
    const int t = threadIdx.x;
    const int base = (blockIdx.x % bpb) * ABLK;

    if (t < G) {
        sgt4[t] = gt[b * G + t];
        skey[t] = KEY_INIT;
        hist[t] = 0;
    }
    {   // 4 KB table: one ulonglong2 (16B) per thread
        const ulonglong2* src = (const ulonglong2*)(tabs + (size_t)b * 512);
        ((ulonglong2*)&tab[0][0])[t] = src[t];
    }

    // Prefetch this thread's anchors (global latency hides under staging).
    // Held in registers through the epilogue (corner recompute source).
    float4 anbuf[APT];
#pragma unroll
    for (int j = 0; j < APT; ++j)
        anbuf[j] = anchors[(size_t)b * A + base + j * BLOCK + t];

    __syncthreads();   // tab ready

    // ---- build: corners + popcount histogram (mask NOT stored: consume
    //      recomputes it from identical inputs -> identical bits) ----
    int pops[APT];
#pragma unroll
    for (int j = 0; j < APT; ++j) {
        const int k = j * BLOCK + t;
        const float4 an = anbuf[j];
        const float ax0 = an.x - 0.5f * an.z;
        const float ay0 = an.y - 0.5f * an.w;
        const float ax1 = an.x + 0.5f * an.z;
        const float ay1 = an.y + 0.5f * an.w;
        sax0[k] = ax0; say0[k] = ay0; sax1[k] = ax1; say1[k] = ay1;

        const unsigned long long mask =
            tab[0][stripclamp(ax1)] & tab[1][stripclamp(ax0)] &
            tab[2][stripclamp(ay1)] & tab[3][stripclamp(ay0)];
        pops[j] = __builtin_popcountll(mask);
        atomicAdd(&hist[pops[j] > 63 ? 63 : pops[j]], 1);
    }
    __syncthreads();

    // ---- one-wave exclusive scan of 64-bin histogram ----
    if (t < G) {
        const int c0 = hist[t];
        int x = c0;
#pragma unroll
        for (int d = 1; d < 64; d <<= 1) {
            int y = __shfl_up(x, d, 64);
            if (t >= d) x += y;
        }
        pfx[t] = x - c0;   // exclusive prefix
    }
    __syncthreads();

    // ---- slot allocation: sorted-by-popcount order ----
#pragma unroll
    for (int j = 0; j < APT; ++j) {
        const int bin = pops[j] > 63 ? 63 : pops[j];
        const int pos = atomicAdd(&pfx[bin], 1);
        sidx[pos] = (unsigned short)(j * BLOCK + t);
    }
    __syncthreads();

    // ---- consume: stratified sorted order; wave pops near-uniform.
    //      Results stashed into the consumed anchor's (now dead) corner
    //      slots; NO global stores here. ----
#pragma unroll
    for (int r = 0; r < APT; ++r) {
        const int k = (int)sidx[r * BLOCK + t];
        const int a = base + k;                      // within-batch anchor id
        const float ax0 = sax0[k], ay0 = say0[k];
        const float ax1 = sax1[k], ay1 = say1[k];
        const float area_a = (ax1 - ax0) * (ay1 - ay0);  // numpy corner-derived

        // recompute mask (bit-identical to build's: same corners, same tab)
        unsigned long long m =
            tab[0][stripclamp(ax1)] & tab[1][stripclamp(ax0)] &
            tab[2][stripclamp(ay1)] & tab[3][stripclamp(ay0)];

        float maxv = 0.0f;   // all-masked row => max_iou 0, argmax 0 (numpy)
        int maxg = 0;
        const unsigned long long inv_p =
            (unsigned long long)(0xFFFFFFFFu - (unsigned)a);

        // merged u64 loop, 2 pairs/iter, ascending g, odd tail duplicates
        // the last real bit (idempotent: strict > fails; same-key atomic
        // no-ops; guard may pass both -> both atomics idempotent).
        // SOFTWARE-PIPELINED GUARD: next pair's sgt4 gathers + skey guard
        // reads issue one iteration ahead -> guard compare never blocks.
        if (m) {
            int g1 = (int)__builtin_ctzll(m);               m &= m - 1;
            int c2 = (int)__builtin_ctzll(m | TOPBIT);
            int g2 = m ? c2 : g1;                           m &= m - 1;
            float4 ga4 = sgt4[g1];
            float4 gb4 = sgt4[g2];
            unsigned long long cur1 = skey[g1];
            unsigned long long cur2 = skey[g2];
            for (;;) {
                const bool more = (m != 0ull);
                // prefetch next pair (dummy g=63 when exhausted: reads only,
                // values unused after break — never dummy atomics)
                const int h1 = (int)__builtin_ctzll(m | TOPBIT); m &= m - 1;
                const int hc = (int)__builtin_ctzll(m | TOPBIT);
                const int h2 = m ? hc : h1;                      m &= m - 1;
                const float4 na = sgt4[h1];
                const float4 nb = sgt4[h2];
                const unsigned long long nc1 = skey[h1];
                const unsigned long long nc2 = skey[h2];

                const float saa = (ga4.z - ga4.x) * (ga4.w - ga4.y);
                const float sab = (gb4.z - gb4.x) * (gb4.w - gb4.y);

                float lxa = fmaxf(ax0, ga4.x), lya = fmaxf(ay0, ga4.y);
                float rxa = fminf(ax1, ga4.z), rya = fminf(ay1, ga4.w);
                float wa = fmaxf(rxa - lxa, 0.0f), ha = fmaxf(rya - lya, 0.0f);
                float intera = wa * ha;
                float unia = area_a + saa - intera;
                float ioua = intera / unia;      // IEEE div: bit-exact vs numpy

                float lxb = fmaxf(ax0, gb4.x), lyb = fmaxf(ay0, gb4.y);
                float rxb = fminf(ax1, gb4.z), ryb = fminf(ay1, gb4.w);
                float wb = fmaxf(rxb - lxb, 0.0f), hb = fmaxf(ryb - lyb, 0.0f);
                float interb = wb * hb;
                float unib = area_a + sab - interb;
                float ioub = interb / unib;      // IEEE div: bit-exact vs numpy

                bool b1 = ioua > maxv; maxv = b1 ? ioua : maxv; maxg = b1 ? g1 : maxg;
                bool b2 = ioub > maxv; maxv = b2 ? ioub : maxv; maxg = b2 ? g2 : maxg;

                const unsigned long long key1 =
                    ((unsigned long long)__float_as_uint(ioua) << 32) | inv_p;
                const unsigned long long key2 =
                    ((unsigned long long)__float_as_uint(ioub) << 32) | inv_p;
                // monotone guard vs one-iteration-old snapshot: stale only
                // under-reads -> skip is provably a no-op; pass always safe.
                if (key1 > cur1) atomicMax(&skey[g1], key1);
                if (key2 > cur2) atomicMax(&skey[g2], key2);

                if (!more) break;
                g1 = h1; g2 = h2; ga4 = na; gb4 = nb; cur1 = nc1; cur2 = nc2;
            }
        }

        // stash results in k's dead corner slots (k consumed exactly once;
        // its corners are never read again by any thread)
        sax0[k] = maxv;
        say0[k] = __uint_as_float((unsigned)maxg);
    }

    __syncthreads();   // results + skey finalized

    // ---- epilogue: NATURAL order, fully coalesced L/M/V stores. Corners
    //      recomputed from this thread's own anbuf registers (identical
    //      expressions on identical inputs -> bit-identical). ----
#pragma unroll
    for (int j = 0; j < APT; ++j) {
        const int k = j * BLOCK + t;
        const size_t idx = (size_t)b * A + (base + k);
        const float4 an = anbuf[j];
        const float ax0 = an.x - 0.5f * an.z;
        const float ay0 = an.y - 0.5f * an.w;
        const float ax1 = an.x + 0.5f * an.z;
        const float ay1 = an.y + 0.5f * an.w;

        const float maxv = sax0[k];                        // stride-256: no conflict
        const int maxg = (int)__float_as_uint(say0[k]);

        const bool fg = maxv > FG_IOU;
        const bool bg = maxv < BG_IOU;
        const bool cross =
            (ax0 < 0.0f) || (ay0 < 0.0f) || (ax1 > IMG) || (ay1 > IMG);

        L[idx] = cross ? -1.0f : (fg ? 1.0f : (bg ? 0.0f : -1.0f));
        float4 mbox = make_float4(0.0f, 0.0f, 0.0f, 0.0f);
        if (fg)  // rare: usually whole-wave skipped; one b128 read
            mbox = sgt4[maxg];
        M[idx] = mbox;
        V[idx] = maxv;
    }

    if (t < G) {
        // unconditional fire-and-forget: every column must receive >=
        // KEY_INIT (gkeys poisoned). skey ordered by the barrier above.
        atomicMax(&gkeys[b * G + t], (long long)skey[t]);
    }
}

// Rule 1 fixup: one block per batch, thread per gt. numpy scatter is
// last-write-wins; thread g writes only if no later g' targets the same anchor.
__global__ void fixup(
    const float4* __restrict__ anchors,
    const float4* __restrict__ gt,
    const long long* __restrict__ gkeys,
    float* __restrict__ L,
    float4* __restrict__ M,
    const float* __restrict__ V,
    int A) {
#pragma clang fp contract(off)
    const int b = blockIdx.x;
    const int g = threadIdx.x;
    __shared__ int tgt[G];

    unsigned long long key = (unsigned long long)gkeys[b * G + g];
    unsigned int a = 0xFFFFFFFFu - (unsigned int)(key & 0xFFFFFFFFull);
    tgt[g] = (int)a;
    __syncthreads();

    bool write = true;
    for (int g2 = g + 1; g2 < G; ++g2)
        if (tgt[g2] == (int)a) { write = false; break; }
    if (!write) return;

    const size_t idx = (size_t)b * A + a;
    float4 an = anchors[idx];
    float ax0 = an.x - 0.5f * an.z;
    float ay0 = an.y - 0.5f * an.w;
    float ax1 = an.x + 0.5f * an.z;
    float ay1 = an.y + 0.5f * an.w;
    bool cross = (ax0 < 0.0f) || (ay0 < 0.0f) || (ax1 > IMG) || (ay1 > IMG);
    // Rule 1 label=1 overrides rule-3 bg; cross filter still wins.
    L[idx] = cross ? -1.0f : 1.0f;
    // Rule 2 (fg) overrides rule 1's matched box; otherwise rule 1 assigns gt[g].
    if (!(V[idx] > FG_IOU)) M[idx] = gt[b * G + g];
}

extern "C" void kernel_launch(void* const* d_in, const int* in_sizes, int n_in,
                              void* d_out, int out_size, void* d_ws, size_t ws_size,
                              hipStream_t stream) {
    const float4* anchors = (const float4*)d_in[0];
    const float4* gt      = (const float4*)d_in[1];
    const int A = in_sizes[0] / (B * 4);

    float* out = (float*)d_out;
    float*  L = out;                                 // [B*A]
    float4* M = (float4*)(out + (size_t)B * A);      // [B*A] float4
    float*  V = out + (size_t)B * A * 5;             // [B*A]

    char* ws = (char*)d_ws;
    long long* gkeys = (long long*)(ws + 256);       // poison 0xAA.. == -inf (i64)
    unsigned long long* tabs = (unsigned long long*)(ws + 8192);  // B*4*128 u64

    const int bpb = A / ABLK;                        // 184320/768 = 240
    build_tables<<<B, 512, 0, stream>>>(gt, tabs);
    assign_main<<<B * bpb, BLOCK, 0, stream>>>(anchors, gt, L, M, V, gkeys,
                                               tabs, A, bpb);
    fixup<<<B, G, 0, stream>>>(anchors, gt, gkeys, L, M, V, A);
}

// Round 14
// 111.266 us; speedup vs baseline: 1.0351x; 1.0351x over previous
//
#include <hip/hip_runtime.h>

// RPN anchor-target assignment. B=8, A=184320, G=64.
// Outputs (flat float32, concatenated): labels[B*A], matched[B*A*4], max_iou[B*A].
// Requires A % 768 == 0 (184320 = 240*768).
//
// Sparse-mask strategy, 3 kernels. Per batch, 4 quantized interval tables
// (u64[128], 5px strips) over the 64 gts; each anchor gets a conservative
// superset mask of possibly-overlapping gts, then exact IEEE IoU only over
// mask bits (~10 avg). Column argmax via LDS u64 atomicMax (order-free exact
// key); block->global device atomicMax.
//
// History: R10 bpermute -> REVERTED. R12 per-pair queue -> REVERTED. R13
// b64+dummies -> REVERTED. R14 counting-sort balancing -> WIN (~40us).
// R15 8 blocks/CU -> win (~38us). R16 gt AoS b128 -> win (~36.5us).
// R17 same-iteration guard reads -> REGRESSION (50us). R18 coalesced stores
// via LDS stash -> best (112.9 total). R19 software-pipelined atomic guard
// -> flat/regression (115.2): atomics EXONERATED (fire-and-forget LDS
// atomicMax was never a throughput cost; guard reads+VGPR cancel any gain).
//
// R20 (this round): pure revert to R18, the measured-best kernel.
//  Every pipe has now been individually A/B-tested: issue count, ILP,
//  occupancy, DS read count, store coalescing, atomic serialization — each
//  <=4% or negative. assign_main (~36us) is distributed across VALU/DS/VMEM
//  with no pipe >~35%; the mask is near-exact (~14.7M pairs ~ true overlap
//  count) so work cannot shrink under bit-exactness. The dominant remaining
//  dur_us term is the harness's 268MB workspace re-poison fills (~77us),
//  not kernel-controllable. This structure is at its practical floor.

constexpr int B = 8;
constexpr int G = 64;
constexpr int BLOCK = 256;
constexpr int APT = 3;                 // anchors per thread
constexpr int ABLK = BLOCK * APT;      // anchors per block = 768
constexpr int NSTRIP = 128;            // 5px strips
constexpr float STRIP_SCALE = 0.2f;
constexpr float STRIP_W = 5.0f;
constexpr float IMG = 640.0f;
constexpr float FG_IOU = 0.7f;
constexpr float BG_IOU = 0.3f;
constexpr float SLACK = 1.0f;
// key(iou=0, anchor=0): correct for an all-zero column (numpy argmax = 0).
constexpr unsigned long long KEY_INIT = 0xFFFFFFFFull;
constexpr unsigned long long TOPBIT = 0x8000000000000000ull;

// ws layout: [256]   u64 gkeys[B*G]      (0xAA poison < 0 as i64 == -inf)
//            [8192]  u64 tabs[B][4][128] (built by build_tables each launch)

// tab0 (xlo): gt.x0 < (s+1)*5 + SLACK   used at s=strip(ax1)  ⊇ gt.x0 < ax1
// tab1 (xhi): gt.x1 > s*5 - SLACK       used at s=strip(ax0)  ⊇ gt.x1 > ax0
// tab2 (ylo): gt.y0 < (s+1)*5 + SLACK   used at s=strip(ay1)  ⊇ gt.y0 < ay1
// tab3 (yhi): gt.y1 > s*5 - SLACK       used at s=strip(ay0)  ⊇ gt.y1 > ay0
__global__ __launch_bounds__(512) void build_tables(
    const float4* __restrict__ gt, unsigned long long* __restrict__ tabs) {
    __shared__ float4 sgt[G];
    const int b = blockIdx.x;
    const int t = threadIdx.x;          // 0..511 = tabIdx*128 + strip
    if (t < G) sgt[t] = gt[b * G + t];
    __syncthreads();
    const int tabIdx = t >> 7;
    const int strip = t & 127;
    const int comp = (tabIdx == 0) ? 0 : (tabIdx == 1) ? 2 : (tabIdx == 2) ? 1 : 3;
    const bool hi = (tabIdx & 1) != 0;
    const float thr = hi ? (strip * STRIP_W - SLACK)
                         : ((strip + 1) * STRIP_W + SLACK);
    unsigned long long m = 0ull;
    for (int g = 0; g < G; ++g) {
        float c = ((const float*)&sgt[g])[comp];
        bool in = hi ? (c > thr) : (c < thr);
        if (in) m |= (1ull << g);
    }
    tabs[(size_t)b * 512 + t] = m;
}

__device__ __forceinline__ int stripclamp(float v) {
    int s = (int)(v * STRIP_SCALE);
    return s < 0 ? 0 : (s > 127 ? 127 : s);
}

__global__ __launch_bounds__(BLOCK, 8) void assign_main(
    const float4* __restrict__ anchors,   // [B*A] cxcywh
    const float4* __restrict__ gt,        // [B*G] xyxy
    float* __restrict__ L,                // labels out [B*A]
    float4* __restrict__ M,               // matched out [B*A]
    float* __restrict__ V,                // max_iou out [B*A]
    long long* __restrict__ gkeys,        // [B*G] global argmax keys (signed max)
    const unsigned long long* __restrict__ tabs,
    int A, int bpb) {
#pragma clang fp contract(off)
    __shared__ float4 sgt4[G];            // gt AoS: ONE b128 read per pair
    __shared__ unsigned long long tab[4][NSTRIP];                 // 4 KB
    __shared__ unsigned long long skey[G];                        // col keys
    __shared__ float sax0[ABLK], say0[ABLK], sax1[ABLK], say1[ABLK]; // 12 KB
    __shared__ unsigned short sidx[ABLK];                         // 1.5 KB
    __shared__ int hist[G];                                       // counts
    __shared__ int pfx[G];                                        // prefix/alloc

    const int b = blockIdx.x / bpb;
    const int t = threadIdx.x;
    const int base = (blockIdx.x % bpb) * ABLK;

    if (t < G) {
        sgt4[t] = gt[b * G + t];
        skey[t] = KEY_INIT;
        hist[t] = 0;
    }
    {   // 4 KB table: one ulonglong2 (16B) per thread
        const ulonglong2* src = (const ulonglong2*)(tabs + (size_t)b * 512);
        ((ulonglong2*)&tab[0][0])[t] = src[t];
    }

    // Prefetch this thread's anchors (global latency hides under staging).
    // Held in registers through the epilogue (corner recompute source).
    float4 anbuf[APT];
#pragma unroll
    for (int j = 0; j < APT; ++j)
        anbuf[j] = anchors[(size_t)b * A + base + j * BLOCK + t];

    __syncthreads();   // tab ready

    // ---- build: corners + popcount histogram (mask NOT stored: consume
    //      recomputes it from identical inputs -> identical bits) ----
    int pops[APT];
#pragma unroll
    for (int j = 0; j < APT; ++j) {
        const int k = j * BLOCK + t;
        const float4 an = anbuf[j];
        const float ax0 = an.x - 0.5f * an.z;
        const float ay0 = an.y - 0.5f * an.w;
        const float ax1 = an.x + 0.5f * an.z;
        const float ay1 = an.y + 0.5f * an.w;
        sax0[k] = ax0; say0[k] = ay0; sax1[k] = ax1; say1[k] = ay1;

        const unsigned long long mask =
            tab[0][stripclamp(ax1)] & tab[1][stripclamp(ax0)] &
            tab[2][stripclamp(ay1)] & tab[3][stripclamp(ay0)];
        pops[j] = __builtin_popcountll(mask);
        atomicAdd(&hist[pops[j] > 63 ? 63 : pops[j]], 1);
    }
    __syncthreads();

    // ---- one-wave exclusive scan of 64-bin histogram ----
    if (t < G) {
        const int c0 = hist[t];
        int x = c0;
#pragma unroll
        for (int d = 1; d < 64; d <<= 1) {
            int y = __shfl_up(x, d, 64);
            if (t >= d) x += y;
        }
        pfx[t] = x - c0;   // exclusive prefix
    }
    __syncthreads();

    // ---- slot allocation: sorted-by-popcount order ----
#pragma unroll
    for (int j = 0; j < APT; ++j) {
        const int bin = pops[j] > 63 ? 63 : pops[j];
        const int pos = atomicAdd(&pfx[bin], 1);
        sidx[pos] = (unsigned short)(j * BLOCK + t);
    }
    __syncthreads();

    // ---- consume: stratified sorted order; wave pops near-uniform.
    //      Results stashed into the consumed anchor's (now dead) corner
    //      slots; NO global stores here. ----
#pragma unroll
    for (int r = 0; r < APT; ++r) {
        const int k = (int)sidx[r * BLOCK + t];
        const int a = base + k;                      // within-batch anchor id
        const float ax0 = sax0[k], ay0 = say0[k];
        const float ax1 = sax1[k], ay1 = say1[k];
        const float area_a = (ax1 - ax0) * (ay1 - ay0);  // numpy corner-derived

        // recompute mask (bit-identical to build's: same corners, same tab)
        unsigned long long m =
            tab[0][stripclamp(ax1)] & tab[1][stripclamp(ax0)] &
            tab[2][stripclamp(ay1)] & tab[3][stripclamp(ay0)];

        float maxv = 0.0f;   // all-masked row => max_iou 0, argmax 0 (numpy)
        int maxg = 0;
        const unsigned long long inv_p =
            (unsigned long long)(0xFFFFFFFFu - (unsigned)a);

        // merged u64 loop, 2 pairs/iter, ascending g, odd tail duplicates the
        // last real bit (idempotent under strict > and same-key atomicMax).
        // Per pair: ONE ds_read_b128 + fire-and-forget atomicMax (no return,
        // no wait — R17/R19 lesson: any skey read in the loop is net-negative).
        while (m) {
            const int g1 = (int)__builtin_ctzll(m);          m &= m - 1;
            const int cand = (int)__builtin_ctzll(m | TOPBIT);
            const int g2 = m ? cand : g1;                    m &= m - 1;

            const float4 ga4 = sgt4[g1];
            const float4 gb4 = sgt4[g2];
            const float saa = (ga4.z - ga4.x) * (ga4.w - ga4.y);
            const float sab = (gb4.z - gb4.x) * (gb4.w - gb4.y);

            float lxa = fmaxf(ax0, ga4.x), lya = fmaxf(ay0, ga4.y);
            float rxa = fminf(ax1, ga4.z), rya = fminf(ay1, ga4.w);
            float wa = fmaxf(rxa - lxa, 0.0f), ha = fmaxf(rya - lya, 0.0f);
            float intera = wa * ha;
            float unia = area_a + saa - intera;
            float ioua = intera / unia;          // IEEE div: bit-exact vs numpy

            float lxb = fmaxf(ax0, gb4.x), lyb = fmaxf(ay0, gb4.y);
            float rxb = fminf(ax1, gb4.z), ryb = fminf(ay1, gb4.w);
            float wb = fmaxf(rxb - lxb, 0.0f), hb = fmaxf(ryb - lyb, 0.0f);
            float interb = wb * hb;
            float unib = area_a + sab - interb;
            float ioub = interb / unib;          // IEEE div: bit-exact vs numpy

            bool b1 = ioua > maxv; maxv = b1 ? ioua : maxv; maxg = b1 ? g1 : maxg;
            bool b2 = ioub > maxv; maxv = b2 ? ioub : maxv; maxg = b2 ? g2 : maxg;

            // iou==0 => key = inv_p <= KEY_INIT: atomicMax natural no-op.
            unsigned long long key1 =
                ((unsigned long long)__float_as_uint(ioua) << 32) | inv_p;
            unsigned long long key2 =
                ((unsigned long long)__float_as_uint(ioub) << 32) | inv_p;
            atomicMax(&skey[g1], key1);
            atomicMax(&skey[g2], key2);
        }

        // stash results in k's dead corner slots (k consumed exactly once;
        // its corners are never read again by any thread)
        sax0[k] = maxv;
        say0[k] = __uint_as_float((unsigned)maxg);
    }

    __syncthreads();   // results + skey finalized

    // ---- epilogue: NATURAL order, fully coalesced L/M/V stores. Corners
    //      recomputed from this thread's own anbuf registers (identical
    //      expressions on identical inputs -> bit-identical). ----
#pragma unroll
    for (int j = 0; j < APT; ++j) {
        const int k = j * BLOCK + t;
        const size_t idx = (size_t)b * A + (base + k);
        const float4 an = anbuf[j];
        const float ax0 = an.x - 0.5f * an.z;
        const float ay0 = an.y - 0.5f * an.w;
        const float ax1 = an.x + 0.5f * an.z;
        const float ay1 = an.y + 0.5f * an.w;

        const float maxv = sax0[k];                        // stride-256: no conflict
        const int maxg = (int)__float_as_uint(say0[k]);

        const bool fg = maxv > FG_IOU;
        const bool bg = maxv < BG_IOU;
        const bool cross =
            (ax0 < 0.0f) || (ay0 < 0.0f) || (ax1 > IMG) || (ay1 > IMG);

        L[idx] = cross ? -1.0f : (fg ? 1.0f : (bg ? 0.0f : -1.0f));
        float4 mbox = make_float4(0.0f, 0.0f, 0.0f, 0.0f);
        if (fg)  // rare: usually whole-wave skipped; one b128 read
            mbox = sgt4[maxg];
        M[idx] = mbox;
        V[idx] = maxv;
    }

    if (t < G) {
        // unconditional fire-and-forget: every column must receive >=
        // KEY_INIT (gkeys poisoned). skey ordered by the barrier above.
        atomicMax(&gkeys[b * G + t], (long long)skey[t]);
    }
}

// Rule 1 fixup: one block per batch, thread per gt. numpy scatter is
// last-write-wins; thread g writes only if no later g' targets the same anchor.
__global__ void fixup(
    const float4* __restrict__ anchors,
    const float4* __restrict__ gt,
    const long long* __restrict__ gkeys,
    float* __restrict__ L,
    float4* __restrict__ M,
    const float* __restrict__ V,
    int A) {
#pragma clang fp contract(off)
    const int b = blockIdx.x;
    const int g = threadIdx.x;
    __shared__ int tgt[G];

    unsigned long long key = (unsigned long long)gkeys[b * G + g];
    unsigned int a = 0xFFFFFFFFu - (unsigned int)(key & 0xFFFFFFFFull);
    tgt[g] = (int)a;
    __syncthreads();

    bool write = true;
    for (int g2 = g + 1; g2 < G; ++g2)
        if (tgt[g2] == (int)a) { write = false; break; }
    if (!write) return;

    const size_t idx = (size_t)b * A + a;
    float4 an = anchors[idx];
    float ax0 = an.x - 0.5f * an.z;
    float ay0 = an.y - 0.5f * an.w;
    float ax1 = an.x + 0.5f * an.z;
    float ay1 = an.y + 0.5f * an.w;
    bool cross = (ax0 < 0.0f) || (ay0 < 0.0f) || (ax1 > IMG) || (ay1 > IMG);
    // Rule 1 label=1 overrides rule-3 bg; cross filter still wins.
    L[idx] = cross ? -1.0f : 1.0f;
    // Rule 2 (fg) overrides rule 1's matched box; otherwise rule 1 assigns gt[g].
    if (!(V[idx] > FG_IOU)) M[idx] = gt[b * G + g];
}

extern "C" void kernel_launch(void* const* d_in, const int* in_sizes, int n_in,
                              void* d_out, int out_size, void* d_ws, size_t ws_size,
                              hipStream_t stream) {
    const float4* anchors = (const float4*)d_in[0];
    const float4* gt      = (const float4*)d_in[1];
    const int A = in_sizes[0] / (B * 4);

    float* out = (float*)d_out;
    float*  L = out;                                 // [B*A]
    float4* M = (float4*)(out + (size_t)B * A);      // [B*A] float4
    float*  V = out + (size_t)B * A * 5;             // [B*A]

    char* ws = (char*)d_ws;
    long long* gkeys = (long long*)(ws + 256);       // poison 0xAA.. == -inf (i64)
    unsigned long long* tabs = (unsigned long long*)(ws + 8192);  // B*4*128 u64

    const int bpb = A / ABLK;                        // 184320/768 = 240
    build_tables<<<B, 512, 0, stream>>>(gt, tabs);
    assign_main<<<B * bpb, BLOCK, 0, stream>>>(anchors, gt, L, M, V, gkeys,
                                               tabs, A, bpb);
    fixup<<<B, G, 0, stream>>>(anchors, gt, gkeys, L, M, V, A);
}